// Round 1
// baseline (435.006 us; speedup 1.0000x reference)
//
#include <hip/hip_runtime.h>

typedef _Float16 f16;
typedef __attribute__((ext_vector_type(8))) _Float16 f16x8;
typedef __attribute__((ext_vector_type(4))) _Float16 f16x4;
typedef __attribute__((ext_vector_type(4))) float f32x4;

// Problem constants
constexpr int BB = 8;
constexpr int NN = 2048;
constexpr int CC = 1024;
constexpr int MTOT = BB * NN;     // 16384
constexpr int KKEEP = 1638;

// ---------------------------------------------------------------------------
// async 16B global -> LDS (HW: dst = wave-uniform base + lane*16)
// ---------------------------------------------------------------------------
__device__ __forceinline__ void gl_lds16(const void* g, void* l) {
  __builtin_amdgcn_global_load_lds((__attribute__((address_space(1))) void*)g,
                                   (__attribute__((address_space(3))) void*)l,
                                   16, 0, 0);
}

// ---------------------------------------------------------------------------
// Unified fp32 -> fp16 conversion: x -> xb, {Wq,Wk,Wv} -> wqkv (concatenated)
// ---------------------------------------------------------------------------
constexpr int X4 = MTOT * CC / 4;   // 4,194,304 vec4
constexpr int W4 = CC * CC / 4;     // 262,144 vec4
__global__ __launch_bounds__(256) void cvt_all(
    const float* __restrict__ x, const float* __restrict__ Wq,
    const float* __restrict__ Wk, const float* __restrict__ Wv,
    f16* __restrict__ xb, f16* __restrict__ wqkv) {
  int i = blockIdx.x * 256 + threadIdx.x;
  const float* s;
  f16* d;
  if (i < X4) { s = x; d = xb; }
  else if (i < X4 + W4) { i -= X4; s = Wq; d = wqkv; }
  else if (i < X4 + 2 * W4) { i -= X4 + W4; s = Wk; d = wqkv + CC * CC; }
  else { i -= X4 + 2 * W4; s = Wv; d = wqkv + 2 * CC * CC; }
  float4 f = ((const float4*)s)[i];
  f16x4 o = {(f16)f.x, (f16)f.y, (f16)f.z, (f16)f.w};
  ((f16x4*)d)[i] = o;
}

// ---------------------------------------------------------------------------
// GEMM-BT core, 256x256 tile, BK=64, 8-phase schedule (T2+T3+T4+T5 port).
//   C[m][n] = sum_k A[m][k] * B[n][k]   (both operands k-contiguous)
//
// 512 threads = 8 waves (2 M x 4 N). Per-wave output 128x64 = acc[8][4] of
// mfma_f32_16x16x32_f16 fragments.  Interleaved sub-tile mapping so each
// phase reads a CONTIGUOUS 128-row LDS half:
//   A row(i) = (i>>2)*128 + wy*64 + (i&3)*16 + id
//   B row(j) = (j>>1)*128 + wx*32 + (j&1)*16 + id
// K-step = 4 phases (qm,qn) = (0,0),(0,1),(1,0),(1,1); 16 MFMA each, wrapped
// in s_setprio(1/0), two raw s_barriers per phase, sched_barrier(0) pins.
//
// LDS: 2 x (A 256x64 + B 256x64) f16 = 128 KiB double buffer, 1 block/CU.
// 3-bit row-XOR source-permute swizzle (proven in prior rounds, 0 bank
// conflicts): LDS slot s of row R holds global k-granule s ^ (R&7); staging
// pre-swizzles the GLOBAL source since global_load_lds writes linearly.
//
// Pipeline (counted vmcnt, never 0 in steady state):
//   chunk issue slots:  A0(s)@P(s-2,2)  B0(s)@P(s-2,3)  A1(s)@P(s-1,0)
//                       B1(s)@P(s-1,1)          (2 global_load_lds each)
//   waits: end of phase0: vmcnt(6)  (retires A1(t),B1(t); 3 chunks stay)
//          end of phase3: vmcnt(8)  (retires A0(t+1),B0(t+1); 4 stay)
//   Overwrite safety: each chunk is issued >=1 end-barrier after the last
//   ds_read of the region it replaces (A half read only in its qm phases,
//   B half only in its qn phases; frags held in regs between uses).
//
// MODE 0: fp32 out, * scale, batched (score S and PV GEMMs)
// MODE 3: fused QKV epilogue: cols [0,2048) -> f16 row-major QK (pitch 2048,
//         bias bq/bk), cols [2048,3072) -> f16 TRANSPOSED Vt[1024][MTOT] +bv.
// ---------------------------------------------------------------------------
#define SBAR __builtin_amdgcn_sched_barrier(0)

#define STAGE_A(buf, h, tt)                                              \
  {                                                                      \
    gl_lds16(gA + (size_t)((h) * 128) * lda + (tt) * 64,                 \
             lA + (buf) * 16384 + (h) * 8192);                           \
    gl_lds16(gA + (size_t)((h) * 128 + 8) * lda + (tt) * 64,             \
             lA + (buf) * 16384 + (h) * 8192 + 512);                     \
  }
#define STAGE_B(buf, h, tt)                                              \
  {                                                                      \
    gl_lds16(gB + (size_t)((h) * 128) * ldb + (tt) * 64,                 \
             lB + (buf) * 16384 + (h) * 8192);                           \
    gl_lds16(gB + (size_t)((h) * 128 + 8) * ldb + (tt) * 64,             \
             lB + (buf) * 16384 + (h) * 8192 + 512);                     \
  }

#define MFMA_Q(qm, qn)                                                   \
  {                                                                      \
    __builtin_amdgcn_s_setprio(1);                                       \
    _Pragma("unroll") for (int kk = 0; kk < 2; kk++)                     \
    _Pragma("unroll") for (int ii = 0; ii < 4; ii++)                     \
    _Pragma("unroll") for (int jj = 0; jj < 2; jj++)                     \
        acc[(qm) * 4 + ii][(qn) * 2 + jj] =                              \
            __builtin_amdgcn_mfma_f32_16x16x32_f16(                      \
                av[kk][ii], bv[kk][(qn) * 2 + jj],                       \
                acc[(qm) * 4 + ii][(qn) * 2 + jj], 0, 0, 0);             \
    __builtin_amdgcn_s_setprio(0);                                       \
  }

template <int MODE>
__global__ __launch_bounds__(512, 2) void gemm_bt(
    const f16* __restrict__ A, const f16* __restrict__ B,
    const float* __restrict__ b0, const float* __restrict__ b1,
    const float* __restrict__ b2, void* __restrict__ Cout,
    void* __restrict__ Cout2, int K, int lda, int ldb, int ldc, float scale,
    long strideA, long strideB, long strideC) {
  const f16* Ab = A + (size_t)blockIdx.z * strideA;
  const f16* Bbp = B + (size_t)blockIdx.z * strideB;

  const int bm = blockIdx.x * 256;
  const int bn = blockIdx.y * 256;
  const int tid = threadIdx.x;
  const int wave = tid >> 6;
  const int lane = tid & 63;
  const int wy = wave >> 2;  // 0..1 (M)
  const int wx = wave & 3;   // 0..3 (N)

  __shared__ __attribute__((aligned(16))) f16 As[2 * 256 * 64];  // 64 KiB
  __shared__ __attribute__((aligned(16))) f16 Bs[2 * 256 * 64];  // 64 KiB

  f32x4 acc[8][4];
#pragma unroll
  for (int i = 0; i < 8; i++)
#pragma unroll
    for (int j = 0; j < 4; j++) acc[i][j] = (f32x4){0.f, 0.f, 0.f, 0.f};

  // staging: wave w owns 16 LDS rows per (half,r-slab); lane l -> row
  // w*16 + r*8 + (l>>3), slot l&7, global granule (l&7)^((l>>3)&7).
  const int srow = wave * 16 + (lane >> 3);
  const int gsrc = ((lane & 7) ^ ((lane >> 3) & 7)) * 8;
  const f16* gA = Ab + (size_t)(bm + srow) * lda + gsrc;
  const f16* gB = Bbp + (size_t)(bn + srow) * ldb + gsrc;
  f16* lA = As + wave * 1024 + lane * 8;
  f16* lB = Bs + wave * 1024 + lane * 8;

  const int NT = K >> 6;

  // prologue: A0(0) B0(0) A1(0) B1(0) [A0(1) B0(1)]; drain first 2 chunks
  STAGE_A(0, 0, 0);
  STAGE_B(0, 0, 0);
  STAGE_A(0, 1, 0);
  STAGE_B(0, 1, 0);
  if (NT > 1) {
    STAGE_A(1, 0, 1);
    STAGE_B(1, 0, 1);
    asm volatile("s_waitcnt vmcnt(8)");
  } else {
    asm volatile("s_waitcnt vmcnt(4)");
  }
  SBAR;
  __builtin_amdgcn_s_barrier();
  SBAR;

  // fragment coords
  const int id = lane & 15;
  const int q = lane >> 4;
  const int g0 = (q ^ (lane & 7)) * 8;        // swizzled slot, kk=0
  const int g1 = ((q + 4) ^ (lane & 7)) * 8;  // kk=1
  const int aoff = (wy * 64 + id) * 64;
  const int boff = (wx * 32 + id) * 64;

  for (int t = 0; t < NT; ++t) {
    const int cur = t & 1;
    const f16* Ac = As + cur * 16384;
    const f16* Bc = Bs + cur * 16384;
    f16x8 av[2][4];  // current qm-half A frags (reused across qn pair)
    f16x8 bv[2][4];  // whole-tile B frags (loaded halves at p0/p1)

    // ---- phase 0: (qm=0, qn=0) ----
#pragma unroll
    for (int ii = 0; ii < 4; ii++) {
      av[0][ii] = *(const f16x8*)(Ac + ii * 1024 + aoff + g0);
      av[1][ii] = *(const f16x8*)(Ac + ii * 1024 + aoff + g1);
    }
#pragma unroll
    for (int jj = 0; jj < 2; jj++) {
      bv[0][jj] = *(const f16x8*)(Bc + jj * 1024 + boff + g0);
      bv[1][jj] = *(const f16x8*)(Bc + jj * 1024 + boff + g1);
    }
    if (t + 1 < NT) STAGE_A(cur ^ 1, 1, t + 1);
    SBAR;
    __builtin_amdgcn_s_barrier();
    SBAR;
    MFMA_Q(0, 0);
    SBAR;
    if (t + 1 < NT) asm volatile("s_waitcnt vmcnt(6)");
    else            asm volatile("s_waitcnt vmcnt(0)");
    __builtin_amdgcn_s_barrier();
    SBAR;

    // ---- phase 1: (qm=0, qn=1) ----
#pragma unroll
    for (int jj = 0; jj < 2; jj++) {
      bv[0][2 + jj] = *(const f16x8*)(Bc + (128 + jj * 16) * 64 + boff + g0);
      bv[1][2 + jj] = *(const f16x8*)(Bc + (128 + jj * 16) * 64 + boff + g1);
    }
    if (t + 1 < NT) STAGE_B(cur ^ 1, 1, t + 1);
    SBAR;
    __builtin_amdgcn_s_barrier();
    SBAR;
    MFMA_Q(0, 1);
    SBAR;
    __builtin_amdgcn_s_barrier();
    SBAR;

    // ---- phase 2: (qm=1, qn=0) ----
#pragma unroll
    for (int ii = 0; ii < 4; ii++) {
      av[0][ii] = *(const f16x8*)(Ac + (128 + ii * 16) * 64 + aoff + g0);
      av[1][ii] = *(const f16x8*)(Ac + (128 + ii * 16) * 64 + aoff + g1);
    }
    if (t + 2 < NT) STAGE_A(cur, 0, t + 2);
    SBAR;
    __builtin_amdgcn_s_barrier();
    SBAR;
    MFMA_Q(1, 0);
    SBAR;
    __builtin_amdgcn_s_barrier();
    SBAR;

    // ---- phase 3: (qm=1, qn=1) ----
    if (t + 2 < NT) STAGE_B(cur, 0, t + 2);
    SBAR;
    __builtin_amdgcn_s_barrier();
    SBAR;
    MFMA_Q(1, 1);
    SBAR;
    if (t + 2 < NT)      asm volatile("s_waitcnt vmcnt(8)");
    else if (t + 1 < NT) asm volatile("s_waitcnt vmcnt(4)");
    __builtin_amdgcn_s_barrier();
    SBAR;
  }

  // epilogue: C/D layout col=lane&15, row=(lane>>4)*4 + r
#pragma unroll
  for (int i = 0; i < 8; i++) {
    const int row0 = bm + (i >> 2) * 128 + wy * 64 + (i & 3) * 16 + q * 4;
#pragma unroll
    for (int j = 0; j < 4; j++) {
      const int col = bn + (j >> 1) * 128 + wx * 32 + (j & 1) * 16 + id;
      if (MODE == 0) {
        float* C = (float*)Cout + (size_t)blockIdx.z * strideC;
#pragma unroll
        for (int r = 0; r < 4; r++)
          C[(size_t)(row0 + r) * ldc + col] = acc[i][j][r] * scale;
      } else {  // MODE 3 — region is uniform per block (bn multiple of 256)
        if (bn < 2048) {
          f16* C = (f16*)Cout;
          const float* bias = (bn < 1024) ? b0 : (b1 - 1024);
          const float bb = bias[col];
#pragma unroll
          for (int r = 0; r < 4; r++)
            C[(size_t)(row0 + r) * 2048 + col] = (f16)(acc[i][j][r] + bb);
        } else {
          f16* C = (f16*)Cout2;
          const float bb = b2[col - 2048];
          f16x4 o;
#pragma unroll
          for (int r = 0; r < 4; r++) o[r] = (f16)(acc[i][j][r] + bb);
          *(f16x4*)(C + (size_t)(col - 2048) * MTOT + row0) = o;
        }
      }
    }
  }
}

// ---------------------------------------------------------------------------
// Per-row exact top-k(1638) + softmax (unchanged).
// Quantized 2048-bin histogram -> threshold bin -> exact tie refinement on
// fp32 value + index. Reads fp32 S (pitch 2048), writes compact f16 P.
// ---------------------------------------------------------------------------
__global__ __launch_bounds__(256) void topk_softmax_kernel(
    const float* __restrict__ S, f16* __restrict__ P) {
  const size_t row = blockIdx.x;
  const float* srow = S + row * 2048;
  f16* prow = P + row * 2048;
  const int t = threadIdx.x;
  const int lane = t & 63;
  const int wave = t >> 6;

  float v[8];
  float4 f0 = ((const float4*)srow)[2 * t];
  float4 f1 = ((const float4*)srow)[2 * t + 1];
  v[0] = f0.x; v[1] = f0.y; v[2] = f0.z; v[3] = f0.w;
  v[4] = f1.x; v[5] = f1.y; v[6] = f1.z; v[7] = f1.w;

  __shared__ float wlo[4], whi[4];
  __shared__ float wf[4];
  __shared__ int wagg[4];
  __shared__ int hist[2048];
  __shared__ float cval[128];
  __shared__ int cidx[128];
  __shared__ int cnum;
  __shared__ int sh_thr, sh_want;

  float lo = v[0], hi = v[0];
#pragma unroll
  for (int j = 1; j < 8; j++) { lo = fminf(lo, v[j]); hi = fmaxf(hi, v[j]); }
#pragma unroll
  for (int off = 32; off > 0; off >>= 1) {
    lo = fminf(lo, __shfl_xor(lo, off, 64));
    hi = fmaxf(hi, __shfl_xor(hi, off, 64));
  }
  if (lane == 0) { wlo[wave] = lo; whi[wave] = hi; }
  if (t == 0) cnum = 0;
  ((int4*)hist)[2 * t] = (int4){0, 0, 0, 0};
  ((int4*)hist)[2 * t + 1] = (int4){0, 0, 0, 0};
  __syncthreads();
  lo = fminf(fminf(wlo[0], wlo[1]), fminf(wlo[2], wlo[3]));
  hi = fmaxf(fmaxf(whi[0], whi[1]), fmaxf(whi[2], whi[3]));

  if (hi == lo) {
    const float w = 1.0f / (float)KKEEP;
    f16x8 o;
#pragma unroll
    for (int j = 0; j < 8; j++) o[j] = (f16)((t * 8 + j < KKEEP) ? w : 0.f);
    *(f16x8*)(prow + t * 8) = o;
    return;
  }

  const float qs = 2048.0f / (hi - lo);
  int key[8];
#pragma unroll
  for (int j = 0; j < 8; j++) {
    int k = (int)((v[j] - lo) * qs);
    key[j] = (k > 2047) ? 2047 : k;
  }
#pragma unroll
  for (int j = 0; j < 8; j++) atomicAdd(&hist[key[j]], 1);
  __syncthreads();

  int4 h0 = ((const int4*)hist)[2 * t];
  int4 h1 = ((const int4*)hist)[2 * t + 1];
  int h[8] = {h0.x, h0.y, h0.z, h0.w, h1.x, h1.y, h1.z, h1.w};
  int s[8];
  s[7] = h[7];
#pragma unroll
  for (int j = 6; j >= 0; j--) s[j] = s[j + 1] + h[j];
  const int partial = s[0];
  int sfx = partial;
#pragma unroll
  for (int off = 1; off < 64; off <<= 1) {
    int o = __shfl_down(sfx, off, 64);
    sfx += (lane + off < 64) ? o : 0;
  }
  if (lane == 0) wagg[wave] = sfx;
  __syncthreads();
  int hiw = 0;
#pragma unroll
  for (int w = 0; w < 4; w++) hiw += (w > wave) ? wagg[w] : 0;
  const int base = (sfx - partial) + hiw;
#pragma unroll
  for (int j = 0; j < 8; j++) {
    const int cum = s[j] + base;
    const int above = cum - h[j];
    if (cum >= KKEEP && above < KKEEP) {
      sh_thr = 8 * t + j;
      sh_want = KKEEP - above;
    }
  }
  __syncthreads();
  const int thr = sh_thr;
  const int wantin = sh_want;

#pragma unroll
  for (int j = 0; j < 8; j++) {
    if (key[j] == thr) {
      int slot = atomicAdd(&cnum, 1);
      if (slot < 128) { cval[slot] = v[j]; cidx[slot] = t * 8 + j; }
    }
  }
  __syncthreads();
  const int n = (cnum < 128) ? cnum : 128;

  float e[8];
  float lsum = 0.f;
#pragma unroll
  for (int j = 0; j < 8; j++) {
    bool kept;
    if (key[j] > thr) {
      kept = true;
    } else if (key[j] < thr) {
      kept = false;
    } else {
      const int myidx = t * 8 + j;
      int rank = 0;
      for (int c = 0; c < n; c++) {
        const float cv = cval[c];
        rank += (cv > v[j] || (cv == v[j] && cidx[c] < myidx)) ? 1 : 0;
      }
      kept = rank < wantin;
    }
    e[j] = kept ? __expf(v[j] - hi) : 0.f;
    lsum += e[j];
  }
#pragma unroll
  for (int off = 32; off > 0; off >>= 1) lsum += __shfl_xor(lsum, off, 64);
  if (lane == 0) wf[wave] = lsum;
  __syncthreads();
  const float inv = 1.0f / (wf[0] + wf[1] + wf[2] + wf[3]);

  f16x8 o;
#pragma unroll
  for (int j = 0; j < 8; j++) o[j] = (f16)(e[j] * inv);
  *(f16x8*)(prow + t * 8) = o;
}

// ---------------------------------------------------------------------------
// launch — 5 dispatches.
// Workspace (peak 224 MiB): [qkb 64M][vtb 32M][S fp32 128M]
//   qkb = [16384][2048] f16: cols 0-1023 Q, 1024-2047 K.
//   xb (32M) + wqkv (6M) aliased into S's span (dead before S written).
//   Pc (compact f16 P, 64M) aliased over qkb (dead after score GEMM).
// ---------------------------------------------------------------------------
extern "C" void kernel_launch(void* const* d_in, const int* in_sizes, int n_in,
                              void* d_out, int out_size, void* d_ws, size_t ws_size,
                              hipStream_t stream) {
  (void)in_sizes; (void)n_in; (void)out_size; (void)ws_size;
  const float* x = (const float*)d_in[0];
  const float* Wq = (const float*)d_in[1];
  const float* bq = (const float*)d_in[2];
  const float* Wk = (const float*)d_in[3];
  const float* bk = (const float*)d_in[4];
  const float* Wv = (const float*)d_in[5];
  const float* bv = (const float*)d_in[6];
  float* out = (float*)d_out;

  char* ws = (char*)d_ws;
  f16* qkb = (f16*)(ws + 0);           // [16384][2048] f16  67,108,864 B
  f16* vtb = (f16*)(ws + 67108864);    // [1024][16384] f16 (V^T)
  float* S = (float*)(ws + 100663296); // [8][2048][2048] fp32 (134,217,728 B)
  // --- aliased into S's span; dead before S is first written ---
  f16* xb = (f16*)(ws + 100663296);    // [16384][1024]
  f16* wqkv = (f16*)(ws + 134217728);  // [3072][1024] (Wq|Wk|Wv rows)
  // --- aliased over qkb; dead after the score GEMM ---
  f16* Pc = (f16*)(ws + 0);            // [8][2048][2048] f16 compact

  // 1) conversions (single dispatch)
  cvt_all<<<(X4 + 3 * W4 + 255) / 256, 256, 0, stream>>>(x, Wq, Wk, Wv, xb, wqkv);

  // 2) fused QKV projection: cols 0-2047 -> qkb, cols 2048-3071 -> vtb (transposed)
  gemm_bt<3><<<dim3(MTOT / 256, 3072 / 256, 1), 512, 0, stream>>>(
      xb, wqkv, bq, bk, bv, qkb, vtb, CC, CC, CC, 0, 1.f, 0, 0, 0);

  // 3) scores S[b] = Q[b] K[b]^T / 32  (fp32 out; overwrites dead xb/wqkv)
  gemm_bt<0><<<dim3(NN / 256, NN / 256, BB), 512, 0, stream>>>(
      qkb, qkb + 1024, nullptr, nullptr, nullptr, S, nullptr, CC, 2048, 2048, NN,
      1.f / 32.f, (long)NN * 2048, (long)NN * 2048, (long)NN * NN);

  // 4) exact top-k + softmax -> compact P f16 (over dead qkb)
  topk_softmax_kernel<<<MTOT, 256, 0, stream>>>(S, Pc);

  // 5) O[b] = P[b] Vt[b]^T  (fp32 out to d_out)
  gemm_bt<0><<<dim3(NN / 256, CC / 256, BB), 512, 0, stream>>>(
      Pc, vtb, nullptr, nullptr, nullptr, out, nullptr, NN, NN, MTOT, CC, 1.f,
      (long)NN * NN, (long)NN, (long)NN * CC);
}